// Round 1
// baseline (1333.937 us; speedup 1.0000x reference)
//
#include <hip/hip_runtime.h>

#define KP   15
#define HN   40
#define CIN  128
#define COUT 128
#define TM   8
#define WSTR (KP*CIN + 4)        // padded stride for s_wt: 1924 floats
#define KP_EXT_INV (1.0f/1.2f)

__global__ __launch_bounds__(256, 2)
void kpconv_fused(const float* __restrict__ q_pts,
                  const float* __restrict__ s_pts,
                  const int*   __restrict__ nb,
                  const float* __restrict__ x,
                  const float* __restrict__ kpts,
                  const float* __restrict__ W,
                  float* __restrict__ out,
                  int N, int Ns)
{
    __shared__ float s_kp[KP*3];
    __shared__ float s_nd[HN*3];
    __shared__ int   s_idx[HN];
    __shared__ float s_w[KP][HN];
    __shared__ float s_wt[TM*WSTR];   // weighted[m][k*128+c], ~61.6 KB

    const int t  = threadIdx.x;
    const int n0 = (int)blockIdx.x * TM;

    if (t < KP*3) s_kp[t] = kpts[t];

    const int c = t & (CIN-1);
    const int g = t >> 7;            // 0 or 1; uniform per wave

    for (int m = 0; m < TM; ++m) {
        const int n = n0 + m;

        // Phase 1a: neighbor offsets (centered on query point)
        if (t < HN) {
            float dx = 1e6f, dy = 1e6f, dz = 1e6f;
            int idx = 0;
            if (n < N) {
                idx = nb[n*HN + t];
                if (idx >= 0 && idx < Ns) {
                    const float qx = q_pts[n*3+0];
                    const float qy = q_pts[n*3+1];
                    const float qz = q_pts[n*3+2];
                    dx = s_pts[idx*3+0] - qx;
                    dy = s_pts[idx*3+1] - qy;
                    dz = s_pts[idx*3+2] - qz;
                } else {
                    idx = 0;   // weight will be 0, feature contribution nil
                }
            }
            s_idx[t] = idx;
            s_nd[t*3+0] = dx; s_nd[t*3+1] = dy; s_nd[t*3+2] = dz;
        }
        __syncthreads();

        // Phase 1b: influence weights w[k][h] = max(0, 1 - |nd-kp|/1.2)
        for (int task = t; task < KP*HN; task += 256) {
            const int k = task / HN;
            const int h = task - k*HN;
            const float dx = s_nd[h*3+0] - s_kp[k*3+0];
            const float dy = s_nd[h*3+1] - s_kp[k*3+1];
            const float dz = s_nd[h*3+2] - s_kp[k*3+2];
            const float d  = sqrtf(dx*dx + dy*dy + dz*dz);
            s_w[k][h] = fmaxf(1.0f - d*KP_EXT_INV, 0.0f);
        }
        __syncthreads();

        // Phase 2: weighted[k][c] = sum_h w[k][h] * x[idx_h][c]
        float acc[8];
        #pragma unroll
        for (int j = 0; j < 8; ++j) acc[j] = 0.0f;

        #pragma unroll 8
        for (int h = 0; h < HN; ++h) {
            const float xv = x[s_idx[h]*CIN + c];
            #pragma unroll
            for (int j = 0; j < 8; ++j) {
                const int k = g + 2*j;
                if (k < KP) acc[j] += s_w[k][h] * xv;
            }
        }
        #pragma unroll
        for (int j = 0; j < 8; ++j) {
            const int k = g + 2*j;
            if (k < KP) s_wt[m*WSTR + k*CIN + c] = acc[j];
        }
        __syncthreads();
    }

    // Phase 3: out[m][d] = sum_{kc} weighted[m][kc] * W[kc][d]
    const int m3 = t >> 5;             // 0..7, uniform per half-wave
    const int d0 = (t & 31) * 4;       // 4 consecutive outputs per thread
    const float* wm = &s_wt[m3*WSTR];

    float ax = 0.f, ay = 0.f, az = 0.f, aw = 0.f;
    #pragma unroll 4
    for (int kc = 0; kc < KP*CIN; ++kc) {
        const float  wv = wm[kc];
        const float4 wr = *(const float4*)&W[kc*COUT + d0];
        ax += wv * wr.x;
        ay += wv * wr.y;
        az += wv * wr.z;
        aw += wv * wr.w;
    }

    const int n = n0 + m3;
    if (n < N) {
        float4 o; o.x = ax; o.y = ay; o.z = az; o.w = aw;
        *(float4*)&out[n*COUT + d0] = o;
    }
}

extern "C" void kernel_launch(void* const* d_in, const int* in_sizes, int n_in,
                              void* d_out, int out_size, void* d_ws, size_t ws_size,
                              hipStream_t stream) {
    const float* q_pts = (const float*)d_in[0];
    const float* s_pts = (const float*)d_in[1];
    const int*   nb    = (const int*)  d_in[2];
    const float* x     = (const float*)d_in[3];
    const float* kpts  = (const float*)d_in[4];
    const float* W     = (const float*)d_in[5];
    float* out = (float*)d_out;

    const int N  = in_sizes[0] / 3;
    const int Ns = in_sizes[1] / 3;
    const int grid = (N + TM - 1) / TM;

    hipLaunchKernelGGL(kpconv_fused, dim3(grid), dim3(256), 0, stream,
                       q_pts, s_pts, nb, x, kpts, W, out, N, Ns);
}

// Round 2
// 164.113 us; speedup vs baseline: 8.1281x; 8.1281x over previous
//
#include <hip/hip_runtime.h>

#define KP   15
#define HN   40
#define CIN  128
#define COUT 128
#define KDIM (KP*CIN)          // 1920
#define KP_EXT_INV (1.0f/1.2f)

typedef __bf16 bf16x8 __attribute__((ext_vector_type(8)));
typedef float  f32x4  __attribute__((ext_vector_type(4)));

__device__ inline void async_copy16(const void* g, void* lds) {
    __builtin_amdgcn_global_load_lds(
        (const __attribute__((address_space(1))) unsigned int*)g,
        (__attribute__((address_space(3))) unsigned int*)lds, 16, 0, 0);
}

// ---------------------------------------------------------------------------
// Kernel 1: W [1920][128] f32  ->  Wt [128][1920] bf16
// ---------------------------------------------------------------------------
__global__ __launch_bounds__(256)
void convert_w(const float* __restrict__ W, __bf16* __restrict__ Bt) {
    const int e  = blockIdx.x * 256 + threadIdx.x;   // over 128*1920
    const int d  = e / KDIM;
    const int kc = e - d * KDIM;
    Bt[e] = (__bf16)W[(size_t)kc * COUT + d];        // coalesced write
}

// ---------------------------------------------------------------------------
// Kernel 2: per-point aggregation via MFMA.
// 1 wave = 1 point. weighted[n][k*128+c] bf16 -> wsA [N][1920]
// ---------------------------------------------------------------------------
#define XSTR 40   // sXt row stride in bf16 (32 h + 8 pad) -> 80 B, 16B-aligned

__global__ __launch_bounds__(256, 2)
void kpconv_aggregate(const float* __restrict__ q_pts,
                      const float* __restrict__ s_pts,
                      const int*   __restrict__ nb,
                      const float* __restrict__ x,
                      const float* __restrict__ kpts,
                      __bf16* __restrict__ wsA,
                      int N, int Ns)
{
    __shared__ __align__(16) __bf16 sXt[4][CIN][XSTR];  // 40960 B
    __shared__ __align__(16) float4 s_nd[4][HN];        // 2560 B
    __shared__ __align__(16) int    s_idx[4][HN];       // 640 B

    const int t  = threadIdx.x;
    const int wv = t >> 6;
    const int l  = t & 63;
    const int n  = blockIdx.x * 4 + wv;   // grid = N/4 exactly

    // ---- geometry: neighbor idx + centered diffs ----
    if (l < HN) {
        int idx = nb[n*HN + l];
        float dx, dy, dz;
        if (idx >= 0 && idx < Ns) {
            dx = s_pts[idx*3+0] - q_pts[n*3+0];
            dy = s_pts[idx*3+1] - q_pts[n*3+1];
            dz = s_pts[idx*3+2] - q_pts[n*3+2];
        } else { idx = 0; dx = dy = dz = 2.0e6f; }
        s_idx[wv][l] = idx;
        s_nd[wv][l]  = make_float4(dx, dy, dz, 0.f);
    }
    __syncthreads();

    // ---- influence weights straight into MFMA A-fragments ----
    // A[m = lane&15][k = (lane>>4)*8 + j], m = kernel point, k = neighbor h
    const int m = l & 15;
    const int q = l >> 4;
    float kx = 0.f, ky = 0.f, kz = 0.f;
    if (m < KP) { kx = kpts[m*3+0]; ky = kpts[m*3+1]; kz = kpts[m*3+2]; }

    bf16x8 wfrag[2];
    #pragma unroll
    for (int ks = 0; ks < 2; ++ks) {
        #pragma unroll
        for (int j = 0; j < 8; ++j) {
            const int h = ks*32 + q*8 + j;
            float w = 0.f;
            if (m < KP && h < HN) {
                float4 nd = s_nd[wv][h];
                float dx = nd.x - kx, dy = nd.y - ky, dz = nd.z - kz;
                float d = sqrtf(dx*dx + dy*dy + dz*dz);
                w = fmaxf(1.0f - d * KP_EXT_INV, 0.f);
            }
            wfrag[ks][j] = (__bf16)w;
        }
    }

    f32x4 acc[8];
    #pragma unroll
    for (int nt = 0; nt < 8; ++nt) acc[nt] = (f32x4){0.f, 0.f, 0.f, 0.f};

    // ---- K-split loop: h in [0,32) then [32,64) (40..63 zero) ----
    for (int ks = 0; ks < 2; ++ks) {
        // stage x^T tile: sXt[c][h_local], bf16
        #pragma unroll
        for (int pass = 0; pass < 2; ++pass) {
            const int c = pass*64 + l;
            const float* xc = x + c;
            #pragma unroll
            for (int hb = 0; hb < 4; ++hb) {
                const int hg0 = ks*32 + hb*8;
                bf16x8 vv;
                if (hg0 < HN) {
                    int4 ia = *(const int4*)&s_idx[wv][hg0];
                    int4 ib = *(const int4*)&s_idx[wv][hg0 + 4];
                    vv[0] = (__bf16)xc[(size_t)ia.x * CIN];
                    vv[1] = (__bf16)xc[(size_t)ia.y * CIN];
                    vv[2] = (__bf16)xc[(size_t)ia.z * CIN];
                    vv[3] = (__bf16)xc[(size_t)ia.w * CIN];
                    vv[4] = (__bf16)xc[(size_t)ib.x * CIN];
                    vv[5] = (__bf16)xc[(size_t)ib.y * CIN];
                    vv[6] = (__bf16)xc[(size_t)ib.z * CIN];
                    vv[7] = (__bf16)xc[(size_t)ib.w * CIN];
                } else {
                    #pragma unroll
                    for (int j = 0; j < 8; ++j) vv[j] = (__bf16)0.f;
                }
                *(bf16x8*)&sXt[wv][c][hb*8] = vv;
            }
        }
        __syncthreads();

        // B-frag: B[k=h][n=c] -> 8 consecutive h at fixed c (row of sXt)
        #pragma unroll
        for (int nt = 0; nt < 8; ++nt) {
            const int c = nt*16 + m;
            bf16x8 bfrag = *(const bf16x8*)&sXt[wv][c][q*8];
            acc[nt] = __builtin_amdgcn_mfma_f32_16x16x32_bf16(
                          wfrag[ks], bfrag, acc[nt], 0, 0, 0);
        }
        __syncthreads();
    }

    // ---- epilogue: D row = q*4+r (kernel pt), col = m (c within tile) ----
    #pragma unroll
    for (int nt = 0; nt < 8; ++nt) {
        #pragma unroll
        for (int r = 0; r < 4; ++r) {
            const int row = q*4 + r;
            if (row < KP) {
                wsA[(size_t)n*KDIM + row*CIN + nt*16 + m] = (__bf16)acc[nt][r];
            }
        }
    }
}

// ---------------------------------------------------------------------------
// Kernel 3: out[M][128] = A[M][1920] (bf16) x Wt[128][1920]^T (bf16), f32 out
// BM=32, BN=128, BK=64. global_load_lds staging + XOR chunk swizzle.
// ---------------------------------------------------------------------------
#define BM 32
#define BK 64

__global__ __launch_bounds__(256, 2)
void kpconv_gemm(const __bf16* __restrict__ A,
                 const __bf16* __restrict__ Bt,
                 float* __restrict__ out, int M)
{
    __shared__ __align__(16) __bf16 sA[BM*BK];    // 4 KB
    __shared__ __align__(16) __bf16 sB[COUT*BK];  // 16 KB

    const int t     = threadIdx.x;
    const int wv    = t >> 6;
    const int l     = t & 63;
    const int mlane = l & 15;
    const int q     = l >> 4;
    const int m0    = blockIdx.x * BM;

    // staging coords: chunk = 16 B = 8 bf16; xor-swizzle chunk within row
    const int ra = t >> 3;                 // row 0..31
    const int ca = t & 7;                  // chunk 0..7
    const int sw = (ca ^ (ra & 7)) * 8;
    const __bf16* gA = A  + (size_t)(m0 + ra) * KDIM + sw;
    const __bf16* gB0 = Bt + (size_t)(0*32 + ra) * KDIM + sw;
    const __bf16* gB1 = Bt + (size_t)(1*32 + ra) * KDIM + sw;
    const __bf16* gB2 = Bt + (size_t)(2*32 + ra) * KDIM + sw;
    const __bf16* gB3 = Bt + (size_t)(3*32 + ra) * KDIM + sw;

    __bf16* dA = &sA[wv*512];              // wave-uniform LDS bases
    __bf16* dB0 = &sB[0*2048 + wv*512];
    __bf16* dB1 = &sB[1*2048 + wv*512];
    __bf16* dB2 = &sB[2*2048 + wv*512];
    __bf16* dB3 = &sB[3*2048 + wv*512];

    f32x4 acc[2][2];
    #pragma unroll
    for (int i = 0; i < 2; ++i)
        #pragma unroll
        for (int j = 0; j < 2; ++j) acc[i][j] = (f32x4){0.f,0.f,0.f,0.f};

    for (int k0 = 0; k0 < KDIM; k0 += BK) {
        async_copy16(gA  + k0, dA);
        async_copy16(gB0 + k0, dB0);
        async_copy16(gB1 + k0, dB1);
        async_copy16(gB2 + k0, dB2);
        async_copy16(gB3 + k0, dB3);
        __syncthreads();

        #pragma unroll
        for (int ks = 0; ks < 2; ++ks) {
            bf16x8 af[2], bf[2];
            #pragma unroll
            for (int mt = 0; mt < 2; ++mt) {
                const int row = mt*16 + mlane;
                const int ch  = (ks*4 + q) ^ (mlane & 7);
                af[mt] = *(const bf16x8*)&sA[row*BK + ch*8];
            }
            #pragma unroll
            for (int j = 0; j < 2; ++j) {
                const int row = (wv*2 + j)*16 + mlane;
                const int ch  = (ks*4 + q) ^ (mlane & 7);
                bf[j] = *(const bf16x8*)&sB[row*BK + ch*8];
            }
            #pragma unroll
            for (int mt = 0; mt < 2; ++mt)
                #pragma unroll
                for (int j = 0; j < 2; ++j)
                    acc[mt][j] = __builtin_amdgcn_mfma_f32_16x16x32_bf16(
                                     af[mt], bf[j], acc[mt][j], 0, 0, 0);
        }
        __syncthreads();
    }

    #pragma unroll
    for (int mt = 0; mt < 2; ++mt)
        #pragma unroll
        for (int j = 0; j < 2; ++j)
            #pragma unroll
            for (int r = 0; r < 4; ++r)
                out[(size_t)(m0 + mt*16 + q*4 + r)*COUT + (wv*2+j)*16 + mlane]
                    = acc[mt][j][r];
}

// ---------------------------------------------------------------------------
// Fallback (round-1 fused kernel, correct but slow) if ws too small
// ---------------------------------------------------------------------------
#define TM 8
#define WSTR (KP*CIN + 4)

__global__ __launch_bounds__(256, 2)
void kpconv_fused(const float* __restrict__ q_pts,
                  const float* __restrict__ s_pts,
                  const int*   __restrict__ nb,
                  const float* __restrict__ x,
                  const float* __restrict__ kpts,
                  const float* __restrict__ W,
                  float* __restrict__ out,
                  int N, int Ns)
{
    __shared__ float s_kp[KP*3];
    __shared__ float s_nd2[HN*3];
    __shared__ int   s_idx2[HN];
    __shared__ float s_w[KP][HN];
    __shared__ float s_wt[TM*WSTR];

    const int t  = threadIdx.x;
    const int n0 = (int)blockIdx.x * TM;
    if (t < KP*3) s_kp[t] = kpts[t];
    const int c = t & (CIN-1);
    const int g = t >> 7;

    for (int m = 0; m < TM; ++m) {
        const int n = n0 + m;
        if (t < HN) {
            float dx = 1e6f, dy = 1e6f, dz = 1e6f;
            int idx = 0;
            if (n < N) {
                idx = nb[n*HN + t];
                if (idx >= 0 && idx < Ns) {
                    dx = s_pts[idx*3+0] - q_pts[n*3+0];
                    dy = s_pts[idx*3+1] - q_pts[n*3+1];
                    dz = s_pts[idx*3+2] - q_pts[n*3+2];
                } else idx = 0;
            }
            s_idx2[t] = idx;
            s_nd2[t*3+0] = dx; s_nd2[t*3+1] = dy; s_nd2[t*3+2] = dz;
        }
        __syncthreads();
        for (int task = t; task < KP*HN; task += 256) {
            const int k = task / HN;
            const int h = task - k*HN;
            const float dx = s_nd2[h*3+0] - s_kp[k*3+0];
            const float dy = s_nd2[h*3+1] - s_kp[k*3+1];
            const float dz = s_nd2[h*3+2] - s_kp[k*3+2];
            s_w[k][h] = fmaxf(1.0f - sqrtf(dx*dx+dy*dy+dz*dz)*KP_EXT_INV, 0.0f);
        }
        __syncthreads();
        float facc[8];
        #pragma unroll
        for (int j = 0; j < 8; ++j) facc[j] = 0.0f;
        #pragma unroll 8
        for (int h = 0; h < HN; ++h) {
            const float xv = x[s_idx2[h]*CIN + c];
            #pragma unroll
            for (int j = 0; j < 8; ++j) {
                const int k = g + 2*j;
                if (k < KP) facc[j] += s_w[k][h] * xv;
            }
        }
        #pragma unroll
        for (int j = 0; j < 8; ++j) {
            const int k = g + 2*j;
            if (k < KP) s_wt[m*WSTR + k*CIN + c] = facc[j];
        }
        __syncthreads();
    }

    const int m3 = t >> 5;
    const int d0 = (t & 31) * 4;
    const float* wm = &s_wt[m3*WSTR];
    float ax = 0.f, ay = 0.f, az = 0.f, aw = 0.f;
    #pragma unroll 4
    for (int kc = 0; kc < KP*CIN; ++kc) {
        const float  wvv = wm[kc];
        const float4 wr = *(const float4*)&W[kc*COUT + d0];
        ax += wvv * wr.x; ay += wvv * wr.y; az += wvv * wr.z; aw += wvv * wr.w;
    }
    const int n = n0 + m3;
    if (n < N) {
        float4 o; o.x = ax; o.y = ay; o.z = az; o.w = aw;
        *(float4*)&out[n*COUT + d0] = o;
    }
}

// ---------------------------------------------------------------------------
extern "C" void kernel_launch(void* const* d_in, const int* in_sizes, int n_in,
                              void* d_out, int out_size, void* d_ws, size_t ws_size,
                              hipStream_t stream) {
    const float* q_pts = (const float*)d_in[0];
    const float* s_pts = (const float*)d_in[1];
    const int*   nb    = (const int*)  d_in[2];
    const float* x     = (const float*)d_in[3];
    const float* kpts  = (const float*)d_in[4];
    const float* W     = (const float*)d_in[5];
    float* out = (float*)d_out;

    const int N  = in_sizes[0] / 3;
    const int Ns = in_sizes[1] / 3;

    const size_t needA = (size_t)N * KDIM * sizeof(__bf16);
    const size_t needB = (size_t)COUT * KDIM * sizeof(__bf16);

    if (ws_size >= needA + needB && (N % 4) == 0 && (N % BM) == 0) {
        __bf16* wsA = (__bf16*)d_ws;
        __bf16* wsB = (__bf16*)((char*)d_ws + needA);
        hipLaunchKernelGGL(convert_w, dim3((COUT*KDIM)/256), dim3(256), 0, stream,
                           W, wsB);
        hipLaunchKernelGGL(kpconv_aggregate, dim3(N/4), dim3(256), 0, stream,
                           q_pts, s_pts, nb, x, kpts, wsA, N, Ns);
        hipLaunchKernelGGL(kpconv_gemm, dim3(N/BM), dim3(256), 0, stream,
                           wsA, wsB, out, N);
    } else {
        const int grid = (N + TM - 1) / TM;
        hipLaunchKernelGGL(kpconv_fused, dim3(grid), dim3(256), 0, stream,
                           q_pts, s_pts, nb, x, kpts, W, out, N, Ns);
    }
}

// Round 3
// 146.115 us; speedup vs baseline: 9.1294x; 1.1232x over previous
//
#include <hip/hip_runtime.h>

#define KP   15
#define HN   40
#define CIN  128
#define COUT 128
#define KDIM (KP*CIN)          // 1920
#define KP_EXT_INV (1.0f/1.2f)

typedef __bf16 bf16x8 __attribute__((ext_vector_type(8)));
typedef float  f32x4  __attribute__((ext_vector_type(4)));

__device__ inline void async_copy16(const void* g, void* lds) {
    __builtin_amdgcn_global_load_lds(
        (const __attribute__((address_space(1))) unsigned int*)g,
        (__attribute__((address_space(3))) unsigned int*)lds, 16, 0, 0);
}

// ---------------------------------------------------------------------------
// Kernel 1 (prep): [blocks 0..nxB)   x f32 -> xb bf16   (coalesced)
//                  [blocks nxB..+60) W [1920][128] f32 -> Wt [128][1920] bf16
// ---------------------------------------------------------------------------
__global__ __launch_bounds__(256)
void kpconv_prep(const float* __restrict__ x, const float* __restrict__ W,
                 __bf16* __restrict__ xb, __bf16* __restrict__ Wt,
                 int nx_elems, int nxB)
{
    __shared__ float sW[32][133];
    const int b = blockIdx.x;
    const int t = threadIdx.x;

    if (b < nxB) {
        const int e0 = (b*256 + t) * 8;
        if (e0 + 8 <= nx_elems) {
            const float4 f0 = *(const float4*)(x + e0);
            const float4 f1 = *(const float4*)(x + e0 + 4);
            bf16x8 v;
            v[0]=(__bf16)f0.x; v[1]=(__bf16)f0.y; v[2]=(__bf16)f0.z; v[3]=(__bf16)f0.w;
            v[4]=(__bf16)f1.x; v[5]=(__bf16)f1.y; v[6]=(__bf16)f1.z; v[7]=(__bf16)f1.w;
            *(bf16x8*)(xb + e0) = v;
        } else {
            for (int e = e0; e < nx_elems; ++e) xb[e] = (__bf16)x[e];
        }
    } else {
        const int kc0 = (b - nxB) * 32;
        // load 32x128 f32 tile, coalesced
        #pragma unroll
        for (int i = 0; i < 4; ++i) {
            const int off = t*4 + i*1024;
            const int r = off >> 7, c = off & 127;
            const float4 f = *(const float4*)(W + (size_t)(kc0 + r)*COUT + c);
            sW[r][c+0]=f.x; sW[r][c+1]=f.y; sW[r][c+2]=f.z; sW[r][c+3]=f.w;
        }
        __syncthreads();
        // write Wt[d][kc0 + ch*8 + j]
        #pragma unroll
        for (int i = 0; i < 2; ++i) {
            const int id = t + i*256;          // 0..511
            const int d  = id >> 2, ch = id & 3;
            bf16x8 v;
            #pragma unroll
            for (int j = 0; j < 8; ++j) v[j] = (__bf16)sW[ch*8 + j][d];
            *(bf16x8*)(Wt + (size_t)d*KDIM + kc0 + ch*8) = v;
        }
    }
}

// ---------------------------------------------------------------------------
// Kernel 2: per-point aggregation via MFMA. 1 wave = 1 point.
// x gathered as bf16x8 vectors, transposed into chunked LDS layout
// sXt[wave][hc][pos][8h] with XOR pos-swizzle (<=2-way banks both sides).
// ---------------------------------------------------------------------------
__global__ __launch_bounds__(256, 4)
void kpconv_aggregate(const float* __restrict__ q_pts,
                      const float* __restrict__ s_pts,
                      const int*   __restrict__ nb,
                      const __bf16* __restrict__ xb,
                      const float* __restrict__ kpts,
                      __bf16* __restrict__ wsA,
                      int N, int Ns)
{
    __shared__ __align__(16) __bf16 sXt[4][4][128][8];  // 32 KB
    __shared__ __align__(16) float4 s_nd[4][HN];
    __shared__ int                  s_idx[4][HN];

    const int t  = threadIdx.x;
    const int wv = t >> 6;
    const int l  = t & 63;
    const int n  = blockIdx.x * 4 + wv;

    // ---- geometry ----
    if (l < HN) {
        int idx = nb[n*HN + l];
        float dx, dy, dz;
        if (idx >= 0 && idx < Ns) {
            dx = s_pts[idx*3+0] - q_pts[n*3+0];
            dy = s_pts[idx*3+1] - q_pts[n*3+1];
            dz = s_pts[idx*3+2] - q_pts[n*3+2];
        } else { idx = 0; dx = dy = dz = 2.0e6f; }
        s_idx[wv][l] = idx;
        s_nd[wv][l]  = make_float4(dx, dy, dz, 0.f);
    }
    __syncthreads();

    // ---- influence weights -> MFMA A-fragments: A[m=kpt][k=h] ----
    const int m = l & 15;
    const int q = l >> 4;
    float kx = 0.f, ky = 0.f, kz = 0.f;
    if (m < KP) { kx = kpts[m*3+0]; ky = kpts[m*3+1]; kz = kpts[m*3+2]; }

    bf16x8 wfrag[2];
    #pragma unroll
    for (int ks = 0; ks < 2; ++ks) {
        #pragma unroll
        for (int j = 0; j < 8; ++j) {
            const int h = ks*32 + q*8 + j;
            float w = 0.f;
            if (m < KP && h < HN) {
                float4 nd = s_nd[wv][h];
                float dx = nd.x - kx, dy = nd.y - ky, dz = nd.z - kz;
                w = fmaxf(1.0f - sqrtf(dx*dx + dy*dy + dz*dz) * KP_EXT_INV, 0.f);
            }
            wfrag[ks][j] = (__bf16)w;
        }
    }

    f32x4 acc[8];
    #pragma unroll
    for (int nt = 0; nt < 8; ++nt) acc[nt] = (f32x4){0.f, 0.f, 0.f, 0.f};

    const int c8 = l & 15;

    for (int ks = 0; ks < 2; ++ks) {
        // stage: lane handles rows (2hp, 2hp+1), chunk c8 (8 consecutive c)
        const int hpBeg = ks ? 16 : 0;
        const int hpEnd = ks ? 20 : 16;
        for (int hp = hpBeg + (l >> 4); hp < hpEnd; hp += 4) {
            const int h0 = 2*hp;
            const uint4 a = *(const uint4*)(xb + (size_t)s_idx[wv][h0  ]*CIN + c8*8);
            const uint4 bb= *(const uint4*)(xb + (size_t)s_idx[wv][h0+1]*CIN + c8*8);
            const unsigned int av[4] = {a.x, a.y, a.z, a.w};
            const unsigned int bv[4] = {bb.x, bb.y, bb.z, bb.w};
            const int hl = h0 - ks*32;          // local row (even)
            const int hc = hl >> 3;             // plane
            const int dw = hp & 3;              // dword within 16B chunk
            unsigned int* plane = (unsigned int*)&sXt[wv][hc][0][0];
            #pragma unroll
            for (int j = 0; j < 8; ++j) {
                const unsigned int lo = (av[j>>1] >> ((j&1)*16)) & 0xFFFFu;
                const unsigned int hi = (bv[j>>1] >> ((j&1)*16)) & 0xFFFFu;
                const int p = c8*8 + (j ^ (c8 & 7));      // swizzled position
                plane[p*4 + dw] = lo | (hi << 16);
            }
        }
        __syncthreads();

        // MFMA: B[k=hl][n=c]; plane q holds hl = q*8..q*8+7.
        // ks=1: planes 1..3 stale but wfrag[1] is zero there (h>=40).
        #pragma unroll
        for (int nt = 0; nt < 8; ++nt) {
            const int cc = nt*16 + m;
            const int p  = (cc & ~7) | ((cc & 7) ^ ((cc >> 3) & 7));
            bf16x8 bfrag = *(const bf16x8*)&sXt[wv][q][p][0];
            acc[nt] = __builtin_amdgcn_mfma_f32_16x16x32_bf16(
                          wfrag[ks], bfrag, acc[nt], 0, 0, 0);
        }
        __syncthreads();
    }

    // ---- epilogue: D col = m, row = q*4+r ----
    #pragma unroll
    for (int nt = 0; nt < 8; ++nt) {
        #pragma unroll
        for (int r = 0; r < 4; ++r) {
            const int row = q*4 + r;
            if (row < KP)
                wsA[(size_t)n*KDIM + row*CIN + nt*16 + m] = (__bf16)acc[nt][r];
        }
    }
}

// ---------------------------------------------------------------------------
// Kernel 3: out[M][128] = A[M][1920] x Wt[128][1920]^T, f32 out.
// BM=32, BN=128, BK=128: 15 K-iters, 16 MFMA/wave/iter, XOR-swizzled DMA.
// ---------------------------------------------------------------------------
#define BM 32
#define BK 128

__global__ __launch_bounds__(256, 2)
void kpconv_gemm(const __bf16* __restrict__ A,
                 const __bf16* __restrict__ Bt,
                 float* __restrict__ out, int M)
{
    __shared__ __align__(16) __bf16 sA[BM*BK];    // 8 KB
    __shared__ __align__(16) __bf16 sB[COUT*BK];  // 32 KB

    const int t     = threadIdx.x;
    const int wv    = t >> 6;
    const int l     = t & 63;
    const int mlane = l & 15;
    const int q     = l >> 4;
    const int m0    = blockIdx.x * BM;

    const int rA = t >> 4;   // 0..15
    const int pA = t & 15;   // stored position; fetched chunk = pA ^ (row&15)

    f32x4 acc[2][2];
    #pragma unroll
    for (int i = 0; i < 2; ++i)
        #pragma unroll
        for (int j = 0; j < 2; ++j) acc[i][j] = (f32x4){0.f,0.f,0.f,0.f};

    for (int k0 = 0; k0 < KDIM; k0 += BK) {
        #pragma unroll
        for (int pass = 0; pass < 2; ++pass) {
            const int r  = rA + pass*16;
            const int ch = pA ^ (r & 15);
            async_copy16(A + (size_t)(m0 + r)*KDIM + k0 + ch*8,
                         (char*)sA + pass*4096 + wv*1024 + l*16);
        }
        #pragma unroll
        for (int pass = 0; pass < 8; ++pass) {
            const int r  = rA + pass*16;
            const int ch = pA ^ (r & 15);
            async_copy16(Bt + (size_t)r*KDIM + k0 + ch*8,
                         (char*)sB + pass*4096 + wv*1024 + l*16);
        }
        __syncthreads();

        #pragma unroll
        for (int ksi = 0; ksi < 4; ++ksi) {
            bf16x8 af[2], bfr[2];
            #pragma unroll
            for (int mt = 0; mt < 2; ++mt) {
                const int row = mt*16 + mlane;
                const int p   = (ksi*4 + q) ^ (row & 15);
                af[mt] = *(const bf16x8*)&sA[row*BK + p*8];
            }
            #pragma unroll
            for (int j = 0; j < 2; ++j) {
                const int row = (wv*2 + j)*16 + mlane;
                const int p   = (ksi*4 + q) ^ (row & 15);
                bfr[j] = *(const bf16x8*)&sB[row*BK + p*8];
            }
            #pragma unroll
            for (int mt = 0; mt < 2; ++mt)
                #pragma unroll
                for (int j = 0; j < 2; ++j)
                    acc[mt][j] = __builtin_amdgcn_mfma_f32_16x16x32_bf16(
                                     af[mt], bfr[j], acc[mt][j], 0, 0, 0);
        }
        __syncthreads();
    }

    #pragma unroll
    for (int mt = 0; mt < 2; ++mt)
        #pragma unroll
        for (int j = 0; j < 2; ++j)
            #pragma unroll
            for (int r = 0; r < 4; ++r)
                out[(size_t)(m0 + mt*16 + q*4 + r)*COUT + (wv*2+j)*16 + mlane]
                    = acc[mt][j][r];
}

// ---------------------------------------------------------------------------
// Fallback (round-1 fused kernel) if ws too small
// ---------------------------------------------------------------------------
#define TM 8
#define WSTR (KP*CIN + 4)

__global__ __launch_bounds__(256, 2)
void kpconv_fused(const float* __restrict__ q_pts,
                  const float* __restrict__ s_pts,
                  const int*   __restrict__ nb,
                  const float* __restrict__ x,
                  const float* __restrict__ kpts,
                  const float* __restrict__ W,
                  float* __restrict__ out,
                  int N, int Ns)
{
    __shared__ float s_kp[KP*3];
    __shared__ float s_nd2[HN*3];
    __shared__ int   s_idx2[HN];
    __shared__ float s_w[KP][HN];
    __shared__ float s_wt[TM*WSTR];

    const int t  = threadIdx.x;
    const int n0 = (int)blockIdx.x * TM;
    if (t < KP*3) s_kp[t] = kpts[t];
    const int c = t & (CIN-1);
    const int g = t >> 7;

    for (int m = 0; m < TM; ++m) {
        const int n = n0 + m;
        if (t < HN) {
            float dx = 1e6f, dy = 1e6f, dz = 1e6f;
            int idx = 0;
            if (n < N) {
                idx = nb[n*HN + t];
                if (idx >= 0 && idx < Ns) {
                    dx = s_pts[idx*3+0] - q_pts[n*3+0];
                    dy = s_pts[idx*3+1] - q_pts[n*3+1];
                    dz = s_pts[idx*3+2] - q_pts[n*3+2];
                } else idx = 0;
            }
            s_idx2[t] = idx;
            s_nd2[t*3+0] = dx; s_nd2[t*3+1] = dy; s_nd2[t*3+2] = dz;
        }
        __syncthreads();
        for (int task = t; task < KP*HN; task += 256) {
            const int k = task / HN;
            const int h = task - k*HN;
            const float dx = s_nd2[h*3+0] - s_kp[k*3+0];
            const float dy = s_nd2[h*3+1] - s_kp[k*3+1];
            const float dz = s_nd2[h*3+2] - s_kp[k*3+2];
            s_w[k][h] = fmaxf(1.0f - sqrtf(dx*dx+dy*dy+dz*dz)*KP_EXT_INV, 0.0f);
        }
        __syncthreads();
        float facc[8];
        #pragma unroll
        for (int j = 0; j < 8; ++j) facc[j] = 0.0f;
        #pragma unroll 8
        for (int h = 0; h < HN; ++h) {
            const float xv = x[s_idx2[h]*CIN + c];
            #pragma unroll
            for (int j = 0; j < 8; ++j) {
                const int k = g + 2*j;
                if (k < KP) facc[j] += s_w[k][h] * xv;
            }
        }
        #pragma unroll
        for (int j = 0; j < 8; ++j) {
            const int k = g + 2*j;
            if (k < KP) s_wt[m*WSTR + k*CIN + c] = facc[j];
        }
        __syncthreads();
    }

    const int m3 = t >> 5;
    const int d0 = (t & 31) * 4;
    const float* wm = &s_wt[m3*WSTR];
    float ax = 0.f, ay = 0.f, az = 0.f, aw = 0.f;
    #pragma unroll 4
    for (int kc = 0; kc < KP*CIN; ++kc) {
        const float  wvv = wm[kc];
        const float4 wr = *(const float4*)&W[kc*COUT + d0];
        ax += wvv * wr.x; ay += wvv * wr.y; az += wvv * wr.z; aw += wvv * wr.w;
    }
    const int n = n0 + m3;
    if (n < N) {
        float4 o; o.x = ax; o.y = ay; o.z = az; o.w = aw;
        *(float4*)&out[n*COUT + d0] = o;
    }
}

// ---------------------------------------------------------------------------
extern "C" void kernel_launch(void* const* d_in, const int* in_sizes, int n_in,
                              void* d_out, int out_size, void* d_ws, size_t ws_size,
                              hipStream_t stream) {
    const float* q_pts = (const float*)d_in[0];
    const float* s_pts = (const float*)d_in[1];
    const int*   nb    = (const int*)  d_in[2];
    const float* x     = (const float*)d_in[3];
    const float* kpts  = (const float*)d_in[4];
    const float* W     = (const float*)d_in[5];
    float* out = (float*)d_out;

    const int N  = in_sizes[0] / 3;
    const int Ns = in_sizes[1] / 3;
    const int nx = in_sizes[3];            // Ns*CIN

    const size_t needA = (size_t)N * KDIM * sizeof(__bf16);
    const size_t needB = (size_t)COUT * KDIM * sizeof(__bf16);
    const size_t needX = (size_t)nx * sizeof(__bf16);

    if (ws_size >= needA + needB + needX && (N % 4) == 0 && (N % BM) == 0
        && (KDIM % 32) == 0) {
        __bf16* wsA = (__bf16*)d_ws;
        __bf16* wsB = (__bf16*)((char*)d_ws + needA);
        __bf16* wsX = (__bf16*)((char*)d_ws + needA + needB);

        const int nxB = (nx/8 + 255) / 256;
        const int nwB = KDIM / 32;
        hipLaunchKernelGGL(kpconv_prep, dim3(nxB + nwB), dim3(256), 0, stream,
                           x, W, wsX, wsB, nx, nxB);
        hipLaunchKernelGGL(kpconv_aggregate, dim3(N/4), dim3(256), 0, stream,
                           q_pts, s_pts, nb, wsX, kpts, wsA, N, Ns);
        hipLaunchKernelGGL(kpconv_gemm, dim3(N/BM), dim3(256), 0, stream,
                           wsA, wsB, out, N);
    } else {
        const int grid = (N + TM - 1) / TM;
        hipLaunchKernelGGL(kpconv_fused, dim3(grid), dim3(256), 0, stream,
                           q_pts, s_pts, nb, x, kpts, W, out, N, Ns);
    }
}